// Round 1
// baseline (6266.830 us; speedup 1.0000x reference)
//
#include <hip/hip_runtime.h>
#include <hip/hip_bf16.h>
#include <math.h>

// Problem constants
#define B_  128
#define C_  256
#define J_  5
#define BS_ 5
#define P_  441          // 21*21
#define N_  2205         // BS_*P_
#define REG_ 1e-6f

// ---------------------------------------------------------------------------
// Kernel 1: per-class channel means over x2.  mean[j][c] = sum_n X[j,n,c] / N
// One wave per (j,c) row; x2 layout [J][Bs][C][21][21].
// ---------------------------------------------------------------------------
__global__ __launch_bounds__(256) void mean_kernel(const float* __restrict__ x2,
                                                   float* __restrict__ mean) {
    const int w    = threadIdx.x >> 6;
    const int lane = threadIdx.x & 63;
    const int j    = blockIdx.x >> 6;          // grid.x = 5*64
    const int c    = (blockIdx.x & 63) * 4 + w;
    float s = 0.f;
    for (int bs = 0; bs < BS_; ++bs) {
        const float* base = x2 + (size_t)((j * BS_ + bs) * C_ + c) * P_;
        #pragma unroll
        for (int k = 0; k < 7; ++k) {
            int p = k * 64 + lane;
            if (p < P_) s += base[p];
        }
    }
    #pragma unroll
    for (int off = 32; off; off >>= 1) s += __shfl_down(s, off);
    if (lane == 0) mean[j * C_ + c] = s * (1.f / (float)N_);
}

// ---------------------------------------------------------------------------
// Kernel 2: per-(b,c) scale = 1/||q||_2 and mu = mean(q*scale) over P.
// One wave per row of x1 [B][C][441].
// ---------------------------------------------------------------------------
__global__ __launch_bounds__(256) void qstats_kernel(const float* __restrict__ x1,
                                                     float* __restrict__ scale,
                                                     float* __restrict__ mu) {
    const int w    = threadIdx.x >> 6;
    const int lane = threadIdx.x & 63;
    const int row  = blockIdx.x * 4 + w;       // 0 .. B_*C_-1
    const float* base = x1 + (size_t)row * P_;
    float s1 = 0.f, s2 = 0.f;
    #pragma unroll
    for (int k = 0; k < 7; ++k) {
        int p = k * 64 + lane;
        if (p < P_) { float v = base[p]; s1 += v; s2 += v * v; }
    }
    #pragma unroll
    for (int off = 32; off; off >>= 1) {
        s1 += __shfl_down(s1, off);
        s2 += __shfl_down(s2, off);
    }
    if (lane == 0) {
        float sc = 1.f / sqrtf(s2);
        scale[row] = sc;
        mu[row]    = s1 * sc * (1.f / (float)P_);
    }
}

// ---------------------------------------------------------------------------
// Kernel 3: raw second-moment matrix covraw[j][c][d] = sum_n X[j,n,c]*X[j,n,d]
// 64x64 tiles, grid (tile=16, j=5, bs=5), atomicAdd accumulate over bs.
// ---------------------------------------------------------------------------
__global__ __launch_bounds__(256) void cov_kernel(const float* __restrict__ x2,
                                                  float* __restrict__ covraw) {
    __shared__ float As[64][33];
    __shared__ float Bs2[64][33];
    const int tid  = threadIdx.x;
    const int tile = blockIdx.x;               // 0..15
    const int j    = blockIdx.y;
    const int bs   = blockIdx.z;
    const int c0   = (tile >> 2) * 64;
    const int d0   = (tile & 3) * 64;
    const float* basec = x2 + (size_t)((j * BS_ + bs) * C_ + c0) * P_;
    const float* based = x2 + (size_t)((j * BS_ + bs) * C_ + d0) * P_;
    const int tcx = tid & 15;                  // d micro
    const int trx = tid >> 4;                  // c micro
    float acc[4][4] = {};
    for (int p0 = 0; p0 < P_; p0 += 32) {
        #pragma unroll
        for (int k = 0; k < 8; ++k) {
            int idx = k * 256 + tid;
            int ci = idx >> 5, ni = idx & 31;
            int p = p0 + ni;
            As[ci][ni]  = (p < P_) ? basec[ci * P_ + p] : 0.f;
            Bs2[ci][ni] = (p < P_) ? based[ci * P_ + p] : 0.f;
        }
        __syncthreads();
        #pragma unroll
        for (int ni = 0; ni < 32; ++ni) {
            float a[4], bb[4];
            #pragma unroll
            for (int i = 0; i < 4; ++i) a[i]  = As[trx * 4 + i][ni];
            #pragma unroll
            for (int i = 0; i < 4; ++i) bb[i] = Bs2[tcx * 4 + i][ni];
            #pragma unroll
            for (int i = 0; i < 4; ++i)
                #pragma unroll
                for (int jj = 0; jj < 4; ++jj)
                    acc[i][jj] += a[i] * bb[jj];
        }
        __syncthreads();
    }
    #pragma unroll
    for (int i = 0; i < 4; ++i)
        #pragma unroll
        for (int jj = 0; jj < 4; ++jj)
            atomicAdd(&covraw[(size_t)j * C_ * C_ + (size_t)(c0 + trx * 4 + i) * C_ +
                              (d0 + tcx * 4 + jj)], acc[i][jj]);
}

// ---------------------------------------------------------------------------
// Kernel 4: assemble cov = (raw - N mu mu^T)/(N-1) + REG*I, then Gauss-Jordan
// in-place inversion (no pivoting; SPD). One block per class, matrix in
// global memory (L2-resident). Workgroup-coherent via __syncthreads.
// ---------------------------------------------------------------------------
__global__ __launch_bounds__(1024) void invert_kernel(const float* __restrict__ covraw,
                                                      const float* __restrict__ mean,
                                                      float* __restrict__ A) {
    const int j   = blockIdx.x;
    const int tid = threadIdx.x;
    __shared__ float piv[256];
    __shared__ float mj[256];
    if (tid < 256) mj[tid] = mean[j * C_ + tid];
    __syncthreads();
    float* Aj = A + (size_t)j * C_ * C_;
    const float* Rj = covraw + (size_t)j * C_ * C_;
    const float invNm1 = 1.f / (float)(N_ - 1);
    // assemble
    for (int k = 0; k < 64; ++k) {
        int e = k * 1024 + tid;
        int r = e >> 8, c = e & 255;
        float v = (Rj[e] - (float)N_ * mj[r] * mj[c]) * invNm1;
        if (r == c) v += REG_;
        Aj[e] = v;
    }
    __syncthreads();
    const int r  = tid >> 2;
    const int cq = tid & 3;
    for (int p = 0; p < 256; ++p) {
        if (tid < 256) piv[tid] = Aj[p * 256 + tid];   // original pivot row
        float g0 = Aj[r * 256 + p];                    // original col-p entry
        __syncthreads();
        float d = 1.f / piv[p];
        if (r == p) {
            #pragma unroll
            for (int i = 0; i < 64; ++i) {
                int c = cq * 64 + i;
                Aj[r * 256 + c] = piv[c] * d;
            }
            if (cq == (p >> 6)) Aj[r * 256 + p] = d;
        } else {
            float g = g0 * d;
            #pragma unroll
            for (int i = 0; i < 64; ++i) {
                int c = cq * 64 + i;
                Aj[r * 256 + c] = Aj[r * 256 + c] - g * piv[c];
            }
            if (cq == (p >> 6)) Aj[r * 256 + p] = -g;
        }
        __syncthreads();
    }
}

// ---------------------------------------------------------------------------
// Kernel 5: the big einsum. Per (p-tile, j, b) block:
//   diff[c][p] = x1[b,c,p]*scale[b,c] - mu[b,c]     (staged in LDS, 64 KB)
//   t[c][p]    = sum_d inv[j][c][d] * diff[d][p]    (inv symmetric: read rows)
//   sim[p]     = sum_c diff[c][p] * t[c][p]
// 512 threads, 4x4 micro-tile, two 128-wide c passes.
// ---------------------------------------------------------------------------
__global__ __launch_bounds__(512) void einsum_kernel(const float* __restrict__ x1,
                                                     const float* __restrict__ inv,
                                                     const float* __restrict__ scale,
                                                     const float* __restrict__ mu,
                                                     float* __restrict__ out) {
    __shared__ float smem[16384];   // diff[256][64]; tail reused as red[32][64]
    const int pt  = blockIdx.x;     // 0..6
    const int j   = blockIdx.y;     // 0..4
    const int b   = blockIdx.z;     // 0..127
    const int tid = threadIdx.x;
    const int p0  = pt * 64;

    // ---- stage diff tile ----
    {
        const int pl = tid & 63;
        const int cg = tid >> 6;    // 0..7
        const int p  = p0 + pl;
        #pragma unroll 4
        for (int k = 0; k < 32; ++k) {
            int c = cg + k * 8;
            float v = 0.f;
            if (p < P_) {
                float sc = scale[b * C_ + c];
                float m  = mu[b * C_ + c];
                v = x1[(size_t)(b * C_ + c) * P_ + p] * sc - m;
            }
            smem[c * 64 + pl] = v;
        }
    }
    __syncthreads();

    const int tc = tid >> 4;        // 0..31  (c groups of 4)
    const int tp = tid & 15;        // 0..15  (p groups of 4)
    const float* invj = inv + (size_t)j * C_ * C_;
    float sim[4] = {0.f, 0.f, 0.f, 0.f};

    #pragma unroll
    for (int pass = 0; pass < 2; ++pass) {
        const int c0t = pass * 128 + tc * 4;
        float acc[4][4] = {};
        #pragma unroll 4
        for (int d = 0; d < 256; ++d) {
            float4 a4 = *(const float4*)&invj[(size_t)d * C_ + c0t];  // inv[c..c+3][d] by symmetry
            float4 b4 = *(const float4*)&smem[d * 64 + tp * 4];
            float av[4] = {a4.x, a4.y, a4.z, a4.w};
            float bv[4] = {b4.x, b4.y, b4.z, b4.w};
            #pragma unroll
            for (int i = 0; i < 4; ++i)
                #pragma unroll
                for (int jj = 0; jj < 4; ++jj)
                    acc[i][jj] += av[i] * bv[jj];
        }
        #pragma unroll
        for (int i = 0; i < 4; ++i) {
            float4 dv = *(const float4*)&smem[(c0t + i) * 64 + tp * 4];
            float dvv[4] = {dv.x, dv.y, dv.z, dv.w};
            #pragma unroll
            for (int jj = 0; jj < 4; ++jj)
                sim[jj] += acc[i][jj] * dvv[jj];
        }
    }
    __syncthreads();                 // diff no longer needed; alias as red
    // red[tc][p] at smem[tc*64 + p]
    #pragma unroll
    for (int jj = 0; jj < 4; ++jj)
        smem[tc * 64 + tp * 4 + jj] = sim[jj];
    __syncthreads();
    if (tid < 64) {
        float s = 0.f;
        #pragma unroll
        for (int k = 0; k < 32; ++k) s += smem[k * 64 + tid];
        int p = p0 + tid;
        if (p < P_) out[(size_t)b * (J_ * P_) + j * P_ + p] = s;
    }
}

// ---------------------------------------------------------------------------
extern "C" void kernel_launch(void* const* d_in, const int* in_sizes, int n_in,
                              void* d_out, int out_size, void* d_ws, size_t ws_size,
                              hipStream_t stream) {
    const float* x1 = (const float*)d_in[0];   // [128,256,21,21]
    const float* x2 = (const float*)d_in[1];   // [5,5,256,21,21]
    float* out = (float*)d_out;                // [128, 5*441]
    float* ws  = (float*)d_ws;

    float* mean   = ws;                                   // 5*256      = 1280
    float* scale  = mean + J_ * C_;                       // 128*256    = 32768
    float* mu     = scale + B_ * C_;                      // 32768
    float* covraw = mu + B_ * C_;                         // 5*256*256  = 327680
    float* Ainv   = covraw + (size_t)J_ * C_ * C_;        // 327680

    hipMemsetAsync(covraw, 0, (size_t)J_ * C_ * C_ * sizeof(float), stream);

    mean_kernel  <<<J_ * 64, 256, 0, stream>>>(x2, mean);
    qstats_kernel<<<(B_ * C_) / 4, 256, 0, stream>>>(x1, scale, mu);
    cov_kernel   <<<dim3(16, J_, BS_), 256, 0, stream>>>(x2, covraw);
    invert_kernel<<<J_, 1024, 0, stream>>>(covraw, mean, Ainv);
    einsum_kernel<<<dim3(7, J_, B_), 512, 0, stream>>>(x1, Ainv, scale, mu, out);
}

// Round 2
// 1422.300 us; speedup vs baseline: 4.4061x; 4.4061x over previous
//
#include <hip/hip_runtime.h>
#include <hip/hip_bf16.h>
#include <math.h>

// Problem constants
#define B_  128
#define C_  256
#define J_  5
#define BS_ 5
#define P_  441          // 21*21
#define N_  2205         // BS_*P_
#define REG_ 1e-6f

// ---------------------------------------------------------------------------
// Kernel 1: per-class channel means over x2.  mean[j][c] = sum_n X[j,n,c] / N
// ---------------------------------------------------------------------------
__global__ __launch_bounds__(256) void mean_kernel(const float* __restrict__ x2,
                                                   float* __restrict__ mean) {
    const int w    = threadIdx.x >> 6;
    const int lane = threadIdx.x & 63;
    const int j    = blockIdx.x >> 6;          // grid.x = 5*64
    const int c    = (blockIdx.x & 63) * 4 + w;
    float s = 0.f;
    for (int bs = 0; bs < BS_; ++bs) {
        const float* base = x2 + (size_t)((j * BS_ + bs) * C_ + c) * P_;
        #pragma unroll
        for (int k = 0; k < 7; ++k) {
            int p = k * 64 + lane;
            if (p < P_) s += base[p];
        }
    }
    #pragma unroll
    for (int off = 32; off; off >>= 1) s += __shfl_down(s, off);
    if (lane == 0) mean[j * C_ + c] = s * (1.f / (float)N_);
}

// ---------------------------------------------------------------------------
// Kernel 2: per-(b,c) scale = 1/||q||_2 and mu = mean(q*scale) over P.
// ---------------------------------------------------------------------------
__global__ __launch_bounds__(256) void qstats_kernel(const float* __restrict__ x1,
                                                     float* __restrict__ scale,
                                                     float* __restrict__ mu) {
    const int w    = threadIdx.x >> 6;
    const int lane = threadIdx.x & 63;
    const int row  = blockIdx.x * 4 + w;       // 0 .. B_*C_-1
    const float* base = x1 + (size_t)row * P_;
    float s1 = 0.f, s2 = 0.f;
    #pragma unroll
    for (int k = 0; k < 7; ++k) {
        int p = k * 64 + lane;
        if (p < P_) { float v = base[p]; s1 += v; s2 += v * v; }
    }
    #pragma unroll
    for (int off = 32; off; off >>= 1) {
        s1 += __shfl_down(s1, off);
        s2 += __shfl_down(s2, off);
    }
    if (lane == 0) {
        float sc = 1.f / sqrtf(s2);
        scale[row] = sc;
        mu[row]    = s1 * sc * (1.f / (float)P_);
    }
}

// ---------------------------------------------------------------------------
// Kernel 3: raw second-moment matrix covraw[j][c][d] = sum_n X[j,n,c]*X[j,n,d]
// ---------------------------------------------------------------------------
__global__ __launch_bounds__(256) void cov_kernel(const float* __restrict__ x2,
                                                  float* __restrict__ covraw) {
    __shared__ float As[64][33];
    __shared__ float Bs2[64][33];
    const int tid  = threadIdx.x;
    const int tile = blockIdx.x;               // 0..15
    const int j    = blockIdx.y;
    const int bs   = blockIdx.z;
    const int c0   = (tile >> 2) * 64;
    const int d0   = (tile & 3) * 64;
    const float* basec = x2 + (size_t)((j * BS_ + bs) * C_ + c0) * P_;
    const float* based = x2 + (size_t)((j * BS_ + bs) * C_ + d0) * P_;
    const int tcx = tid & 15;                  // d micro
    const int trx = tid >> 4;                  // c micro
    float acc[4][4] = {};
    for (int p0 = 0; p0 < P_; p0 += 32) {
        #pragma unroll
        for (int k = 0; k < 8; ++k) {
            int idx = k * 256 + tid;
            int ci = idx >> 5, ni = idx & 31;
            int p = p0 + ni;
            As[ci][ni]  = (p < P_) ? basec[ci * P_ + p] : 0.f;
            Bs2[ci][ni] = (p < P_) ? based[ci * P_ + p] : 0.f;
        }
        __syncthreads();
        #pragma unroll
        for (int ni = 0; ni < 32; ++ni) {
            float a[4], bb[4];
            #pragma unroll
            for (int i = 0; i < 4; ++i) a[i]  = As[trx * 4 + i][ni];
            #pragma unroll
            for (int i = 0; i < 4; ++i) bb[i] = Bs2[tcx * 4 + i][ni];
            #pragma unroll
            for (int i = 0; i < 4; ++i)
                #pragma unroll
                for (int jj = 0; jj < 4; ++jj)
                    acc[i][jj] += a[i] * bb[jj];
        }
        __syncthreads();
    }
    #pragma unroll
    for (int i = 0; i < 4; ++i)
        #pragma unroll
        for (int jj = 0; jj < 4; ++jj)
            atomicAdd(&covraw[(size_t)j * C_ * C_ + (size_t)(c0 + trx * 4 + i) * C_ +
                              (d0 + tcx * 4 + jj)], acc[i][jj]);
}

// ---------------------------------------------------------------------------
// Kernel 4: register-resident Gauss-Jordan inversion. One block per class.
// Thread t owns row r = t>>2, cols [cq*64, cq*64+64) in registers (own[64]).
// Per pivot step p:
//   - g (col-p entry of each row) was captured into gnext during step p-1;
//     broadcast within the 4-thread row group via __shfl.
//   - row-p threads dump their registers to LDS prow[] (static indices);
//     owner of (p,p) also writes pv_sh and sets prow[p] += 1 so the generic
//     update own[c] -= g*d*prow[c] produces -g*d at c == p automatically.
//   - all threads update their 64 registers; capture col-(p+1) value.
// ---------------------------------------------------------------------------
__global__ __launch_bounds__(1024) void invert_kernel(const float* __restrict__ covraw,
                                                      const float* __restrict__ mean,
                                                      float* __restrict__ Ainv) {
    const int j    = blockIdx.x;
    const int t    = threadIdx.x;
    const int r    = t >> 2;
    const int cq   = t & 3;
    const int ci0  = cq * 64;
    const int lane = t & 63;

    __shared__ float prow[4 * 68];   // skew 68 floats/chunk: aligned + conflict-free
    __shared__ float pv_sh;
    __shared__ float mj[256];

    if (t < 256) mj[t] = mean[j * C_ + t];
    __syncthreads();

    float own[64];
    const float invNm1 = 1.f / (float)(N_ - 1);
    {
        const float* Rr = covraw + (size_t)j * C_ * C_ + (size_t)r * C_ + ci0;
        const float* mc = &mj[ci0];
        const float murN = mj[r] * (float)N_;
        #pragma unroll
        for (int i4 = 0; i4 < 16; ++i4) {
            float4 rv = *(const float4*)&Rr[i4 * 4];
            float4 mv = *(const float4*)&mc[i4 * 4];
            float v[4] = { (rv.x - murN * mv.x) * invNm1,
                           (rv.y - murN * mv.y) * invNm1,
                           (rv.z - murN * mv.z) * invNm1,
                           (rv.w - murN * mv.w) * invNm1 };
            #pragma unroll
            for (int k = 0; k < 4; ++k) {
                int i = i4 * 4 + k;
                if (ci0 + i == r) v[k] += REG_;
                own[i] = v[k];
            }
        }
    }
    float gnext = own[0];            // col-0 value (valid where cq==0)

    for (int p = 0; p < 256; ++p) {
        // broadcast this row's col-p entry from the owning cq lane
        float g = __shfl(gnext, (lane & 60) | (p >> 6));
        if (r == p) {
            #pragma unroll
            for (int i4 = 0; i4 < 16; ++i4)
                *(float4*)&prow[cq * 68 + i4 * 4] =
                    make_float4(own[i4 * 4], own[i4 * 4 + 1],
                                own[i4 * 4 + 2], own[i4 * 4 + 3]);
            if (cq == (p >> 6)) {
                pv_sh = gnext;                       // pivot value
                prow[cq * 68 + (p & 63)] = gnext + 1.f;  // +1 trick for col p
            }
        }
        __syncthreads();
        const float d  = 1.f / pv_sh;
        const float gd = g * d;
        if (r == p) {
            #pragma unroll
            for (int i4 = 0; i4 < 16; ++i4) {
                float4 pr = *(const float4*)&prow[cq * 68 + i4 * 4];
                #pragma unroll
                for (int k = 0; k < 4; ++k) {
                    int i = i4 * 4 + k;
                    float pri = (&pr.x)[k];
                    float v = (ci0 + i == p) ? d : pri * d;
                    own[i] = v;
                    if (ci0 + i == p + 1) gnext = v;
                }
            }
        } else {
            #pragma unroll
            for (int i4 = 0; i4 < 16; ++i4) {
                float4 pr = *(const float4*)&prow[cq * 68 + i4 * 4];
                #pragma unroll
                for (int k = 0; k < 4; ++k) {
                    int i = i4 * 4 + k;
                    float pri = (&pr.x)[k];
                    float v = fmaf(-gd, pri, own[i]);   // prow[p] has +1 -> v = -gd there
                    own[i] = v;
                    if (ci0 + i == p + 1) gnext = v;
                }
            }
        }
        __syncthreads();
    }

    float* Or = Ainv + (size_t)j * C_ * C_ + (size_t)r * C_ + ci0;
    #pragma unroll
    for (int i4 = 0; i4 < 16; ++i4)
        *(float4*)&Or[i4 * 4] = make_float4(own[i4 * 4], own[i4 * 4 + 1],
                                            own[i4 * 4 + 2], own[i4 * 4 + 3]);
}

// ---------------------------------------------------------------------------
// Kernel 5: the big einsum. Per (p-tile, j, b) block:
//   diff[c][p] = x1[b,c,p]*scale[b,c] - mu[b,c]     (staged in LDS, 64 KB)
//   sim[p]     = sum_c diff[c][p] * (inv diff)[c][p]
// ---------------------------------------------------------------------------
__global__ __launch_bounds__(512) void einsum_kernel(const float* __restrict__ x1,
                                                     const float* __restrict__ inv,
                                                     const float* __restrict__ scale,
                                                     const float* __restrict__ mu,
                                                     float* __restrict__ out) {
    __shared__ float smem[16384];   // diff[256][64]; tail reused as red[32][64]
    const int pt  = blockIdx.x;     // 0..6
    const int j   = blockIdx.y;     // 0..4
    const int b   = blockIdx.z;     // 0..127
    const int tid = threadIdx.x;
    const int p0  = pt * 64;

    // ---- stage diff tile ----
    {
        const int pl = tid & 63;
        const int cg = tid >> 6;    // 0..7
        const int p  = p0 + pl;
        #pragma unroll 4
        for (int k = 0; k < 32; ++k) {
            int c = cg + k * 8;
            float v = 0.f;
            if (p < P_) {
                float sc = scale[b * C_ + c];
                float m  = mu[b * C_ + c];
                v = x1[(size_t)(b * C_ + c) * P_ + p] * sc - m;
            }
            smem[c * 64 + pl] = v;
        }
    }
    __syncthreads();

    const int tc = tid >> 4;        // 0..31  (c groups of 4)
    const int tp = tid & 15;        // 0..15  (p groups of 4)
    const float* invj = inv + (size_t)j * C_ * C_;
    float sim[4] = {0.f, 0.f, 0.f, 0.f};

    #pragma unroll
    for (int pass = 0; pass < 2; ++pass) {
        const int c0t = pass * 128 + tc * 4;
        float acc[4][4] = {};
        #pragma unroll 4
        for (int d = 0; d < 256; ++d) {
            float4 a4 = *(const float4*)&invj[(size_t)d * C_ + c0t];  // inv[c..c+3][d] by symmetry
            float4 b4 = *(const float4*)&smem[d * 64 + tp * 4];
            float av[4] = {a4.x, a4.y, a4.z, a4.w};
            float bv[4] = {b4.x, b4.y, b4.z, b4.w};
            #pragma unroll
            for (int i = 0; i < 4; ++i)
                #pragma unroll
                for (int jj = 0; jj < 4; ++jj)
                    acc[i][jj] += av[i] * bv[jj];
        }
        #pragma unroll
        for (int i = 0; i < 4; ++i) {
            float4 dv = *(const float4*)&smem[(c0t + i) * 64 + tp * 4];
            float dvv[4] = {dv.x, dv.y, dv.z, dv.w};
            #pragma unroll
            for (int jj = 0; jj < 4; ++jj)
                sim[jj] += acc[i][jj] * dvv[jj];
        }
    }
    __syncthreads();                 // diff no longer needed; alias as red
    #pragma unroll
    for (int jj = 0; jj < 4; ++jj)
        smem[tc * 64 + tp * 4 + jj] = sim[jj];
    __syncthreads();
    if (tid < 64) {
        float s = 0.f;
        #pragma unroll
        for (int k = 0; k < 32; ++k) s += smem[k * 64 + tid];
        int p = p0 + tid;
        if (p < P_) out[(size_t)b * (J_ * P_) + j * P_ + p] = s;
    }
}

// ---------------------------------------------------------------------------
extern "C" void kernel_launch(void* const* d_in, const int* in_sizes, int n_in,
                              void* d_out, int out_size, void* d_ws, size_t ws_size,
                              hipStream_t stream) {
    const float* x1 = (const float*)d_in[0];   // [128,256,21,21]
    const float* x2 = (const float*)d_in[1];   // [5,5,256,21,21]
    float* out = (float*)d_out;                // [128, 5*441]
    float* ws  = (float*)d_ws;

    float* mean   = ws;                                   // 5*256
    float* scale  = mean + J_ * C_;                       // 128*256
    float* mu     = scale + B_ * C_;                      // 128*256
    float* covraw = mu + B_ * C_;                         // 5*256*256
    float* Ainv   = covraw + (size_t)J_ * C_ * C_;        // 5*256*256

    hipMemsetAsync(covraw, 0, (size_t)J_ * C_ * C_ * sizeof(float), stream);

    mean_kernel  <<<J_ * 64, 256, 0, stream>>>(x2, mean);
    qstats_kernel<<<(B_ * C_) / 4, 256, 0, stream>>>(x1, scale, mu);
    cov_kernel   <<<dim3(16, J_, BS_), 256, 0, stream>>>(x2, covraw);
    invert_kernel<<<J_, 1024, 0, stream>>>(covraw, mean, Ainv);
    einsum_kernel<<<dim3(7, J_, B_), 512, 0, stream>>>(x1, Ainv, scale, mu, out);
}

// Round 3
// 535.445 us; speedup vs baseline: 11.7040x; 2.6563x over previous
//
#include <hip/hip_runtime.h>
#include <hip/hip_bf16.h>
#include <math.h>

// Problem constants
#define B_  128
#define C_  256
#define J_  5
#define BS_ 5
#define P_  441          // 21*21
#define N_  2205         // BS_*P_
#define REG_ 1e-6f

typedef __attribute__((ext_vector_type(8))) short short8_t;   // 8 bf16 (4 VGPR)
typedef __attribute__((ext_vector_type(4))) float f32x4;

__device__ __forceinline__ unsigned short f2bf(float f) {     // RNE f32->bf16
    union { float f; unsigned int u; } x; x.f = f;
    unsigned int r = (x.u + 0x7FFFu + ((x.u >> 16) & 1u)) >> 16;
    return (unsigned short)r;
}
__device__ __forceinline__ float bf2f(unsigned short u) {
    union { unsigned int u; float f; } x; x.u = ((unsigned int)u) << 16;
    return x.f;
}

// ---------------------------------------------------------------------------
// Kernel 1: per-class channel means over x2.
// ---------------------------------------------------------------------------
__global__ __launch_bounds__(256) void mean_kernel(const float* __restrict__ x2,
                                                   float* __restrict__ mean) {
    const int w    = threadIdx.x >> 6;
    const int lane = threadIdx.x & 63;
    const int j    = blockIdx.x >> 6;
    const int c    = (blockIdx.x & 63) * 4 + w;
    float s = 0.f;
    for (int bs = 0; bs < BS_; ++bs) {
        const float* base = x2 + (size_t)((j * BS_ + bs) * C_ + c) * P_;
        #pragma unroll
        for (int k = 0; k < 7; ++k) {
            int p = k * 64 + lane;
            if (p < P_) s += base[p];
        }
    }
    #pragma unroll
    for (int off = 32; off; off >>= 1) s += __shfl_down(s, off);
    if (lane == 0) mean[j * C_ + c] = s * (1.f / (float)N_);
}

// ---------------------------------------------------------------------------
// Kernel 2: per-(b,c) scale = 1/||q||_2 and mu = mean(q*scale) over P.
// ---------------------------------------------------------------------------
__global__ __launch_bounds__(256) void qstats_kernel(const float* __restrict__ x1,
                                                     float* __restrict__ scale,
                                                     float* __restrict__ mu) {
    const int w    = threadIdx.x >> 6;
    const int lane = threadIdx.x & 63;
    const int row  = blockIdx.x * 4 + w;
    const float* base = x1 + (size_t)row * P_;
    float s1 = 0.f, s2 = 0.f;
    #pragma unroll
    for (int k = 0; k < 7; ++k) {
        int p = k * 64 + lane;
        if (p < P_) { float v = base[p]; s1 += v; s2 += v * v; }
    }
    #pragma unroll
    for (int off = 32; off; off >>= 1) {
        s1 += __shfl_down(s1, off);
        s2 += __shfl_down(s2, off);
    }
    if (lane == 0) {
        float sc = 1.f / sqrtf(s2);
        scale[row] = sc;
        mu[row]    = s1 * sc * (1.f / (float)P_);
    }
}

// ---------------------------------------------------------------------------
// Kernel 3: raw second-moment covraw[j][c][d] = sum_n X[j,n,c]*X[j,n,d]
// ---------------------------------------------------------------------------
__global__ __launch_bounds__(256) void cov_kernel(const float* __restrict__ x2,
                                                  float* __restrict__ covraw) {
    __shared__ float As[64][33];
    __shared__ float Bs2[64][33];
    const int tid  = threadIdx.x;
    const int tile = blockIdx.x;
    const int j    = blockIdx.y;
    const int bs   = blockIdx.z;
    const int c0   = (tile >> 2) * 64;
    const int d0   = (tile & 3) * 64;
    const float* basec = x2 + (size_t)((j * BS_ + bs) * C_ + c0) * P_;
    const float* based = x2 + (size_t)((j * BS_ + bs) * C_ + d0) * P_;
    const int tcx = tid & 15;
    const int trx = tid >> 4;
    float acc[4][4] = {};
    for (int p0 = 0; p0 < P_; p0 += 32) {
        #pragma unroll
        for (int k = 0; k < 8; ++k) {
            int idx = k * 256 + tid;
            int ci = idx >> 5, ni = idx & 31;
            int p = p0 + ni;
            As[ci][ni]  = (p < P_) ? basec[ci * P_ + p] : 0.f;
            Bs2[ci][ni] = (p < P_) ? based[ci * P_ + p] : 0.f;
        }
        __syncthreads();
        #pragma unroll
        for (int ni = 0; ni < 32; ++ni) {
            float a[4], bb[4];
            #pragma unroll
            for (int i = 0; i < 4; ++i) a[i]  = As[trx * 4 + i][ni];
            #pragma unroll
            for (int i = 0; i < 4; ++i) bb[i] = Bs2[tcx * 4 + i][ni];
            #pragma unroll
            for (int i = 0; i < 4; ++i)
                #pragma unroll
                for (int jj = 0; jj < 4; ++jj)
                    acc[i][jj] += a[i] * bb[jj];
        }
        __syncthreads();
    }
    #pragma unroll
    for (int i = 0; i < 4; ++i)
        #pragma unroll
        for (int jj = 0; jj < 4; ++jj)
            atomicAdd(&covraw[(size_t)j * C_ * C_ + (size_t)(c0 + trx * 4 + i) * C_ +
                              (d0 + tcx * 4 + jj)], acc[i][jj]);
}

// ---------------------------------------------------------------------------
// Kernel 4: BLOCKED register-resident Gauss-Jordan (16-pivot panels).
// Thread t owns row r=t>>2, col quarter cq=t&3 (own[64]). Wave w holds rows
// 16w..16w+15. Per block step s (panel = rows/cols 16s..16s+15):
//  1. wave s publishes its 16x256 rows to LDS slab PL; all other rows with
//     cq==qp publish their 16 panel-col values to Bb.
//  2. wave s runs 16 scalar GJ pivots on PL (intra-wave, no barriers),
//     reads back its rows, then adds +1 at the 16 diagonal positions so the
//     trailing update's generic FMA emits the inverse-part columns.
//  3. all non-panel rows: own[c] -= sum_i Bb[r][i] * PL[i][c]  (rank-16).
// Output written as bf16 (row-major, symmetric).
// ---------------------------------------------------------------------------
__global__ __launch_bounds__(1024) void invert_kernel(const float* __restrict__ covraw,
                                                      const float* __restrict__ mean,
                                                      unsigned short* __restrict__ invb) {
    const int j    = blockIdx.x;
    const int t    = threadIdx.x;
    const int r    = t >> 2;
    const int cq   = t & 3;
    const int ci0  = cq * 64;
    const int w    = t >> 6;
    const int lane = t & 63;

    __shared__ float PL[16 * 272];   // slab: row rr, col c at rr*272 + (c>>6)*68 + (c&63)
    __shared__ float Bb[256 * 20];   // B-hat: row r, 16 coeffs (pad 20)
    __shared__ float mj[256];

    if (t < 256) mj[t] = mean[j * C_ + t];
    __syncthreads();

    float own[64];
    {
        const float* Rr = covraw + (size_t)j * 65536 + (size_t)r * 256 + ci0;
        const float murN   = mj[r] * (float)N_;
        const float invNm1 = 1.f / (float)(N_ - 1);
        #pragma unroll
        for (int i4 = 0; i4 < 16; ++i4) {
            float4 rv = *(const float4*)&Rr[i4 * 4];
            float4 mv = *(const float4*)&mj[ci0 + i4 * 4];
            float v0 = (rv.x - murN * mv.x) * invNm1;
            float v1 = (rv.y - murN * mv.y) * invNm1;
            float v2 = (rv.z - murN * mv.z) * invNm1;
            float v3 = (rv.w - murN * mv.w) * invNm1;
            if (ci0 + i4 * 4 + 0 == r) v0 += REG_;
            if (ci0 + i4 * 4 + 1 == r) v1 += REG_;
            if (ci0 + i4 * 4 + 2 == r) v2 += REG_;
            if (ci0 + i4 * 4 + 3 == r) v3 += REG_;
            own[i4 * 4 + 0] = v0; own[i4 * 4 + 1] = v1;
            own[i4 * 4 + 2] = v2; own[i4 * 4 + 3] = v3;
        }
    }

    for (int s = 0; s < 16; ++s) {
        const int p0 = s * 16;
        const int qp = p0 >> 6;
        const int co = p0 & 63;
        const bool panelRow = ((r >> 4) == s);

        // ---- 1. publish ----
        if (w == s) {
            #pragma unroll
            for (int i4 = 0; i4 < 16; ++i4)
                *(float4*)&PL[(r & 15) * 272 + cq * 68 + i4 * 4] =
                    make_float4(own[i4 * 4], own[i4 * 4 + 1], own[i4 * 4 + 2], own[i4 * 4 + 3]);
        } else if (cq == qp) {
            #pragma unroll
            for (int i4 = 0; i4 < 64; ++i4) {
                int ii = i4 - co;             // global col ci0+i4 == p0+ii
                if (ii >= 0 && ii < 16) Bb[r * 20 + ii] = own[i4];   // uniform branch
            }
        }
        __syncthreads();

        // ---- 2. panel elimination (wave s only, intra-wave) ----
        if (w == s) {
            const int coff = (lane >> 4) * 68 + (lane & 15) * 4;  // lane's 4-col chunk
            #pragma unroll
            for (int i = 0; i < 16; ++i) {
                const int pvoff = qp * 68 + co + i;               // pivot col LDS offset
                const bool haspiv = (lane == ((p0 + i) >> 2));
                float pv = PL[i * 272 + pvoff];                   // broadcast read
                float d  = 1.f / pv;
                // normalize pivot row chunk
                float4 pr = *(const float4*)&PL[i * 272 + coff];
                pr.x *= d; pr.y *= d; pr.z *= d; pr.w *= d;
                if (haspiv) ((float*)&pr)[i & 3] = d;             // i&3 is constant
                *(float4*)&PL[i * 272 + coff] = pr;
                // update the other 15 rows, 4 at a time
                #pragma unroll
                for (int rb = 0; rb < 4; ++rb) {
                    float  g[4];
                    float4 v[4];
                    #pragma unroll
                    for (int u = 0; u < 4; ++u) {
                        int rr = rb * 4 + u;
                        g[u] = PL[rr * 272 + pvoff];
                        v[u] = *(const float4*)&PL[rr * 272 + coff];
                    }
                    #pragma unroll
                    for (int u = 0; u < 4; ++u) {
                        int rr = rb * 4 + u;
                        if (rr == i) continue;                    // static skip
                        float4 nv;
                        nv.x = fmaf(-g[u], pr.x, v[u].x);
                        nv.y = fmaf(-g[u], pr.y, v[u].y);
                        nv.z = fmaf(-g[u], pr.z, v[u].z);
                        nv.w = fmaf(-g[u], pr.w, v[u].w);
                        if (haspiv) ((float*)&nv)[i & 3] = -g[u] * d;
                        *(float4*)&PL[rr * 272 + coff] = nv;
                    }
                }
            }
            // read back final physical rows into registers
            #pragma unroll
            for (int i4 = 0; i4 < 16; ++i4) {
                float4 v = *(const float4*)&PL[(r & 15) * 272 + cq * 68 + i4 * 4];
                own[i4 * 4 + 0] = v.x; own[i4 * 4 + 1] = v.y;
                own[i4 * 4 + 2] = v.z; own[i4 * 4 + 3] = v.w;
            }
            // +I at diagonal (AFTER readback; enables the trailing FMA trick)
            if (lane < 16) PL[lane * 272 + qp * 68 + co + lane] += 1.f;
        }
        __syncthreads();

        // ---- 3. trailing rank-16 update ----
        if (!panelRow) {
            float bh[16];
            #pragma unroll
            for (int u = 0; u < 4; ++u) {
                float4 b4 = *(const float4*)&Bb[r * 20 + u * 4];
                bh[u * 4 + 0] = b4.x; bh[u * 4 + 1] = b4.y;
                bh[u * 4 + 2] = b4.z; bh[u * 4 + 3] = b4.w;
            }
            #pragma unroll
            for (int i = 0; i < 16; ++i) {
                const float bi = bh[i];
                #pragma unroll
                for (int i4 = 0; i4 < 16; ++i4) {
                    float4 p4 = *(const float4*)&PL[i * 272 + cq * 68 + i4 * 4];
                    own[i4 * 4 + 0] = fmaf(-bi, p4.x, own[i4 * 4 + 0]);
                    own[i4 * 4 + 1] = fmaf(-bi, p4.y, own[i4 * 4 + 1]);
                    own[i4 * 4 + 2] = fmaf(-bi, p4.z, own[i4 * 4 + 2]);
                    own[i4 * 4 + 3] = fmaf(-bi, p4.w, own[i4 * 4 + 3]);
                }
            }
        }
        __syncthreads();
    }

    // epilogue: bf16 store
    unsigned short* dst = invb + (size_t)j * 65536 + (size_t)r * 256 + ci0;
    #pragma unroll
    for (int i4 = 0; i4 < 16; ++i4) {
        ushort4 o;
        o.x = f2bf(own[i4 * 4 + 0]); o.y = f2bf(own[i4 * 4 + 1]);
        o.z = f2bf(own[i4 * 4 + 2]); o.w = f2bf(own[i4 * 4 + 3]);
        *(ushort4*)&dst[i4 * 4] = o;
    }
}

// ---------------------------------------------------------------------------
// Kernel 5: MFMA einsum. Per (pt,b) block (256 thr = 4 waves):
//   stage diffT[p][c] bf16 in LDS (XOR swizzle (p&7)<<4), p-tile of 112;
//   for each j: t = inv_j * diff via mfma_f32_16x16x32_bf16 (gemm_bt pattern:
//   A rows = inv rows (k contiguous), B rows = diffT rows (k contiguous)),
//   then sim[p] = sum_m diffT[p][m] * t[m][p] reduced across lanes/waves.
// ---------------------------------------------------------------------------
__global__ __launch_bounds__(256) void einsum_kernel(const float* __restrict__ x1,
                                                     const unsigned short* __restrict__ invb,
                                                     const float* __restrict__ scale,
                                                     const float* __restrict__ mu,
                                                     float* __restrict__ out) {
    __shared__ unsigned short dT[112 * 256];   // byte addr = p*512 + c*2, ^((p&7)<<4)
    __shared__ float simbuf[4][7][16];
    char* dTc = (char*)dT;

    const int pt = blockIdx.x;                 // 0..3
    const int b  = blockIdx.y;                 // 0..127
    const int t  = threadIdx.x;
    const int p0 = pt * 112;
    const int w    = t >> 6;
    const int lane = t & 63;

    // ---- stage diffT ----
    {
        const int g32 = t >> 5;                // 0..7
        const int l32 = t & 31;
        for (int cc = 0; cc < 32; ++cc) {
            const int c = g32 * 32 + cc;
            const float sc = scale[b * C_ + c];
            const float m  = mu[b * C_ + c];
            const float* xr = x1 + (size_t)(b * C_ + c) * P_ + p0;
            #pragma unroll
            for (int mm = 0; mm < 4; ++mm) {
                int p = mm * 32 + l32;
                if (p < 112) {
                    float v = 0.f;
                    if (p0 + p < P_) v = xr[p] * sc - m;
                    int byte = (p * 512 + c * 2) ^ ((p & 7) << 4);
                    *(unsigned short*)(dTc + byte) = f2bf(v);
                }
            }
        }
    }
    __syncthreads();

    for (int j = 0; j < J_; ++j) {
        const unsigned short* invj = invb + (size_t)j * 65536;
        f32x4 acc[4][7];
        #pragma unroll
        for (int mt = 0; mt < 4; ++mt)
            #pragma unroll
            for (int nt = 0; nt < 7; ++nt)
                acc[mt][nt] = (f32x4){0.f, 0.f, 0.f, 0.f};

        for (int kt = 0; kt < 8; ++kt) {
            const int k = kt * 32 + (lane >> 4) * 8;
            short8_t a[4], bb[7];
            #pragma unroll
            for (int mt = 0; mt < 4; ++mt) {
                int m = w * 64 + mt * 16 + (lane & 15);
                a[mt] = *(const short8_t*)(invj + (size_t)m * 256 + k);
            }
            #pragma unroll
            for (int nt = 0; nt < 7; ++nt) {
                int n = nt * 16 + (lane & 15);
                int byte = (n * 512 + k * 2) ^ ((n & 7) << 4);
                bb[nt] = *(const short8_t*)(dTc + byte);
            }
            #pragma unroll
            for (int mt = 0; mt < 4; ++mt)
                #pragma unroll
                for (int nt = 0; nt < 7; ++nt)
                    acc[mt][nt] = __builtin_amdgcn_mfma_f32_16x16x32_bf16(
                        a[mt], bb[nt], acc[mt][nt], 0, 0, 0);
        }

        // ---- dot with diff + reduce ----
        float sim[7];
        #pragma unroll
        for (int nt = 0; nt < 7; ++nt) sim[nt] = 0.f;
        #pragma unroll
        for (int mt = 0; mt < 4; ++mt) {
            const int m = w * 64 + mt * 16 + (lane >> 4) * 4;
            #pragma unroll
            for (int nt = 0; nt < 7; ++nt) {
                const int n = nt * 16 + (lane & 15);
                int byte = (n * 512 + m * 2) ^ ((n & 7) << 4);
                ushort4 du = *(const ushort4*)(dTc + byte);
                sim[nt] += bf2f(du.x) * acc[mt][nt][0];
                sim[nt] += bf2f(du.y) * acc[mt][nt][1];
                sim[nt] += bf2f(du.z) * acc[mt][nt][2];
                sim[nt] += bf2f(du.w) * acc[mt][nt][3];
            }
        }
        #pragma unroll
        for (int nt = 0; nt < 7; ++nt) {
            float v = sim[nt];
            v += __shfl_xor(v, 16);
            v += __shfl_xor(v, 32);
            if (lane < 16) simbuf[w][nt][lane] = v;
        }
        __syncthreads();
        if (t < 112) {
            const int nt = t >> 4;
            float s = simbuf[0][nt][t & 15] + simbuf[1][nt][t & 15] +
                      simbuf[2][nt][t & 15] + simbuf[3][nt][t & 15];
            int p = p0 + t;
            if (p < P_) out[(size_t)b * (J_ * P_) + j * P_ + p] = s;
        }
        __syncthreads();
    }
}

// ---------------------------------------------------------------------------
extern "C" void kernel_launch(void* const* d_in, const int* in_sizes, int n_in,
                              void* d_out, int out_size, void* d_ws, size_t ws_size,
                              hipStream_t stream) {
    const float* x1 = (const float*)d_in[0];   // [128,256,21,21]
    const float* x2 = (const float*)d_in[1];   // [5,5,256,21,21]
    float* out = (float*)d_out;                // [128, 5*441]
    float* ws  = (float*)d_ws;

    float* mean   = ws;                                   // 1280
    float* scale  = mean + J_ * C_;                       // 32768
    float* mu     = scale + B_ * C_;                      // 32768
    float* covraw = mu + B_ * C_;                         // 327680
    unsigned short* invb = (unsigned short*)(covraw + (size_t)J_ * C_ * C_);  // 327680 bf16

    hipMemsetAsync(covraw, 0, (size_t)J_ * C_ * C_ * sizeof(float), stream);

    mean_kernel  <<<J_ * 64, 256, 0, stream>>>(x2, mean);
    qstats_kernel<<<(B_ * C_) / 4, 256, 0, stream>>>(x1, scale, mu);
    cov_kernel   <<<dim3(16, J_, BS_), 256, 0, stream>>>(x2, covraw);
    invert_kernel<<<J_, 1024, 0, stream>>>(covraw, mean, invb);
    einsum_kernel<<<dim3(4, B_), 256, 0, stream>>>(x1, invb, scale, mu, out);
}